// Round 8
// baseline (183.518 us; speedup 1.0000x reference)
//
#include <hip/hip_runtime.h>
#include <hip/hip_bf16.h>
#include <math.h>

// R8: transpose-free MFMA chain via 16x16x16 (K=16) shapes.
//   Layout identity: 16x16x16 B-operand B[k=q*4+j][n=c] == C/D layout
//   (row=q*4+r, col=c). So layer1 D (transposed orientation, D1[f][p]) feeds
//   layer2 directly after in-register leaky+bf16 pack. No LDS transpose.
//   Per 16-pt tile: ds_read_b64 feat B-frag -> 4 MFMA L1 -> leaky/pack ->
//   16 MFMA L2 (C init = b2) -> epilogue dot W3 + q-reduce. 4 tiles/group,
//   fully unrolled (independent chains). Patch table (R7) for gathers.
//   LDS = 8 KB/block (feature ping-pong only).

#define NTHREADS 256
#define NB 4  // 64-point groups per wave

typedef __attribute__((ext_vector_type(4))) short s16x4;  // 4 bf16 = 2 VGPRs
typedef __attribute__((ext_vector_type(4))) float f32x4;
typedef __attribute__((ext_vector_type(4))) int i32x4;
typedef __attribute__((ext_vector_type(2))) int i32x2;

static __device__ __forceinline__ short f2bf(float f) {
    return __builtin_bit_cast(short, __float2bfloat16(f));  // RNE
}
static __device__ __forceinline__ int pk2(float lo, float hi) {
    unsigned short l = (unsigned short)f2bf(lo);
    unsigned short h = (unsigned short)f2bf(hi);
    return (int)(((unsigned int)h << 16) | (unsigned int)l);
}
static __device__ __forceinline__ float bflo(int u) {
    return __builtin_bit_cast(float, u << 16);
}
static __device__ __forceinline__ float bfhi(int u) {
    return __builtin_bit_cast(float, (int)(u & 0xffff0000));
}

// ---- preproc: pack 2x2 corner patches (bf16), both grids in one launch ----
// patch[id=(y0<<8)|x0]: int[8]: [0..2]=(bl<<16)|tl per ch, [3..5]=(br<<16)|tr.
__global__ __launch_bounds__(256) void make_patches(
    const float* __restrict__ gP, const float* __restrict__ gD,
    int* __restrict__ outP, int* __restrict__ outD) {
    int gid = blockIdx.x * 256 + threadIdx.x;  // 0..131071
    const float* g = (gid < 65536) ? gP : gD;
    int* po = (gid < 65536) ? outP : outD;
    int id = gid & 65535;
    int y0 = id >> 8, x0 = id & 255;
    int x1 = min(x0 + 1, 255), y1 = min(y0 + 1, 255);
    const float* tl = g + (y0 * 256 + x0) * 3;
    const float* tr = g + (y0 * 256 + x1) * 3;
    const float* bl = g + (y1 * 256 + x0) * 3;
    const float* br = g + (y1 * 256 + x1) * 3;
    i32x4 u0;
    i32x2 u1;
    u0[0] = pk2(tl[0], bl[0]);
    u0[1] = pk2(tl[1], bl[1]);
    u0[2] = pk2(tl[2], bl[2]);
    u0[3] = pk2(tr[0], br[0]);
    u1[0] = pk2(tr[1], br[1]);
    u1[1] = pk2(tr[2], br[2]);
    *(i32x4*)(po + id * 8) = u0;
    *(i32x2*)(po + id * 8 + 4) = u1;
}

static __device__ __forceinline__ void patch_issue(
    const int* __restrict__ tab, float px, float py, int* P, float& xf,
    float& yf) {
    float fx = px * 255.0f;
    float fy = py * 255.0f;
    int x0 = (int)fx;      // trunc, fx >= 0
    int y0 = (int)fy;
    xf = fx - floorf(fx);  // jnp.mod(fx,1.0), fx >= 0
    yf = fy - floorf(fy);
    int idx = (y0 << 8) | x0;
    i32x4 a = *(const i32x4*)(tab + idx * 8);
    i32x2 b = *(const i32x2*)(tab + idx * 8 + 4);
    P[0] = a[0]; P[1] = a[1]; P[2] = a[2];
    P[3] = a[3]; P[4] = b[0]; P[5] = b[1];
}

static __device__ __forceinline__ void patch_lerp(const int* P, float xf,
                                                  float yf, float* f) {
#pragma unroll
    for (int ch = 0; ch < 3; ++ch) {
        float tl = bflo(P[ch]), bl = bfhi(P[ch]);
        float tr = bflo(P[ch + 3]), br = bfhi(P[ch + 3]);
        float top = fmaf(xf, tr - tl, tl);
        float bot = fmaf(xf, br - bl, bl);
        f[ch] = fmaf(yf, bot - top, top);
    }
}

__global__ __launch_bounds__(NTHREADS, 4) void mlp_mfma_kernel(
    const float* __restrict__ pos, const float* __restrict__ dir,
    const int* __restrict__ patP, const int* __restrict__ patD,
    const float* __restrict__ W1, const float* __restrict__ b1,
    const float* __restrict__ W2, const float* __restrict__ b2,
    const float* __restrict__ W3, const float* __restrict__ b3,
    float* __restrict__ out) {
    __shared__ int lds_F[4 * 2 * 64 * 4];  // feature ping-pong, 8192 B

    const int w = threadIdx.x >> 6;
    const int lane = threadIdx.x & 63;
    const int c = lane & 15;
    const int q = lane >> 4;

    int* FB = lds_F + w * (2 * 64 * 4);

    // ---- resident weight fragments (16x16x16: A[m=lane&15][k=q*4+j]) ----
    // layer1: A[m=f][k]; f = mt*16+c, k = q*4+j. k<6: W1; k==6: b1; else 0
    // (k>=8, i.e. q>=2, is zero -> garbage B halves there contribute 0).
    s16x4 A1f[4];
#pragma unroll
    for (int mt = 0; mt < 4; ++mt) {
        int f = mt * 16 + c;
        s16x4 t;
#pragma unroll
        for (int j = 0; j < 4; ++j) {
            int k = q * 4 + j;
            float v = 0.0f;
            if (k < 6) v = W1[f * 6 + k];
            else if (k == 6) v = b1[f];
            t[j] = f2bf(v);
        }
        A1f[mt] = t;
    }
    // layer2: A[m=n2][k=f]; n2 = mt*16+c, k = kt*16 + q*4 + j.
    s16x4 A2f[4][4];  // [kt][mt]
#pragma unroll
    for (int kt = 0; kt < 4; ++kt)
#pragma unroll
        for (int mt = 0; mt < 4; ++mt) {
            int n2 = mt * 16 + c;
            int k0 = kt * 16 + q * 4;
            s16x4 t;
#pragma unroll
            for (int j = 0; j < 4; ++j) t[j] = f2bf(W2[n2 * 64 + k0 + j]);
            A2f[kt][mt] = t;
        }
    // epilogue constants: n2 = mt*16 + q*4 + r (C-layout rows)
    f32x4 ci[4], w3q[4];
#pragma unroll
    for (int mt = 0; mt < 4; ++mt)
#pragma unroll
        for (int r = 0; r < 4; ++r) {
            ci[mt][r] = b2[mt * 16 + q * 4 + r];
            w3q[mt][r] = W3[mt * 16 + q * 4 + r];
        }
    const float b3s = b3[0];
    const int dbias = pk2(1.0f, 0.0f);
    const f32x4 zacc = {0.f, 0.f, 0.f, 0.f};

    const long wave_global = (long)blockIdx.x * 4 + w;
    const long base0 = wave_global * (64L * NB);
    const float2* pos2 = (const float2*)pos;
    const float2* dir2 = (const float2*)dir;

    // ---- pipeline state: patches for group ib+1, coords for group ib+2 ----
    int PA[12];
    float frA[4];
    float2 cpn, cdn;

    // ---- prologue ----
    {
        float2 c0p = pos2[base0 + lane], c0d = dir2[base0 + lane];
        float2 c1p = pos2[base0 + 64 + lane], c1d = dir2[base0 + 64 + lane];
        cpn = pos2[base0 + 128 + lane];
        cdn = dir2[base0 + 128 + lane];
        int P0_[12];
        float fr0[4];
        patch_issue(patP, c0p.x, c0p.y, P0_, fr0[0], fr0[1]);
        patch_issue(patD, c0d.x, c0d.y, P0_ + 6, fr0[2], fr0[3]);
        float feat[6];
        patch_lerp(P0_, fr0[0], fr0[1], feat);
        patch_lerp(P0_ + 6, fr0[2], fr0[3], feat + 3);
        i32x4 dv;
        dv[0] = pk2(feat[0], feat[1]);
        dv[1] = pk2(feat[2], feat[3]);
        dv[2] = pk2(feat[4], feat[5]);
        dv[3] = dbias;
        *(i32x4*)(FB + lane * 4) = dv;  // buf 0, row = point
        patch_issue(patP, c1p.x, c1p.y, PA, frA[0], frA[1]);
        patch_issue(patD, c1d.x, c1d.y, PA + 6, frA[2], frA[3]);
    }

#pragma unroll 1
    for (int ib = 0; ib < NB; ++ib) {
        const long base = base0 + ib * 64;
        const int cur = ib & 1;

        // issue patches for group ib+2 (coords loaded 2 iters ago)
        int PB[12];
        float frB[4];
        patch_issue(patP, cpn.x, cpn.y, PB, frB[0], frB[1]);
        patch_issue(patD, cdn.x, cdn.y, PB + 6, frB[2], frB[3]);

        // features for group ib+1 (patches issued one full iter ago)
        {
            float feat[6];
            patch_lerp(PA, frA[0], frA[1], feat);
            patch_lerp(PA + 6, frA[2], frA[3], feat + 3);
            i32x4 dv;
            dv[0] = pk2(feat[0], feat[1]);
            dv[1] = pk2(feat[2], feat[3]);
            dv[2] = pk2(feat[4], feat[5]);
            dv[3] = dbias;
            *(i32x4*)(FB + (cur ^ 1) * 256 + lane * 4) = dv;
        }

        // ---- 4 tiles of 16 points; fully unrolled, independent chains ----
        float s[4];
#pragma unroll
        for (int t = 0; t < 4; ++t) {
            // feature B-frag: B[k=q*4+j][n=c], point = t*16+c.
            // q=0,1 read halves 0..7 (k 0..7); q=2,3 re-read (A is 0 there).
            i32x2 bi = *(const i32x2*)(FB + cur * 256 + (t * 16 + c) * 4 +
                                       (q & 1) * 2);
            s16x4 bfeat = __builtin_bit_cast(s16x4, bi);

            // layer 1: D1[f][p], 4 f-tiles, one K-tile
            f32x4 a1[4];
#pragma unroll
            for (int mt = 0; mt < 4; ++mt)
                a1[mt] = __builtin_amdgcn_mfma_f32_16x16x16bf16_1k(
                    A1f[mt], bfeat, zacc, 0, 0, 0);

            // leaky + pack: D1 C-layout == next B-layout (k=f), no transpose
            s16x4 bh[4];
#pragma unroll
            for (int kt = 0; kt < 4; ++kt) {
                s16x4 hv;
#pragma unroll
                for (int r = 0; r < 4; ++r) {
                    float x = a1[kt][r];
                    hv[r] = f2bf(fmaxf(x, 0.01f * x));
                }
                bh[kt] = hv;
            }

            // layer 2: D2[n2][p], C init = b2
            f32x4 a2[4];
#pragma unroll
            for (int mt = 0; mt < 4; ++mt) a2[mt] = ci[mt];
#pragma unroll
            for (int kt = 0; kt < 4; ++kt)
#pragma unroll
                for (int mt = 0; mt < 4; ++mt)
                    a2[mt] = __builtin_amdgcn_mfma_f32_16x16x16bf16_1k(
                        A2f[kt][mt], bh[kt], a2[mt], 0, 0, 0);

            // epilogue: leaky, dot W3 over this lane's 16 n2 rows, q-reduce
            float tt = 0.0f;
#pragma unroll
            for (int mt = 0; mt < 4; ++mt)
#pragma unroll
                for (int r = 0; r < 4; ++r) {
                    float x = a2[mt][r];
                    x = fmaxf(x, 0.01f * x);
                    tt = fmaf(x, w3q[mt][r], tt);
                }
            tt += __shfl_xor(tt, 16, 64);
            tt += __shfl_xor(tt, 32, 64);
            s[t] = tt;  // sum for point t*16 + c, in all quads
        }

        // lane (c,q) emits point q*16 + c with value s[q]
        float sa = (q & 1) ? s[1] : s[0];
        float sb = (q & 1) ? s[3] : s[2];
        float v = (q & 2) ? sb : sa;
        v += b3s;
        v = 1.0f / (1.0f + __expf(-v));
        out[base + q * 16 + c] = v;

        // ---- rotate pipeline ----
#pragma unroll
        for (int i2 = 0; i2 < 12; ++i2) PA[i2] = PB[i2];
        frA[0] = frB[0]; frA[1] = frB[1]; frA[2] = frB[2]; frA[3] = frB[3];
        int mb = min(ib + 3, NB - 1);
        cpn = pos2[base0 + mb * 64 + lane];
        cdn = dir2[base0 + mb * 64 + lane];
    }
}

extern "C" void kernel_launch(void* const* d_in, const int* in_sizes, int n_in,
                              void* d_out, int out_size, void* d_ws,
                              size_t ws_size, hipStream_t stream) {
    const float* pos = (const float*)d_in[0];
    const float* dir = (const float*)d_in[1];
    const float* pos_grid = (const float*)d_in[2];
    const float* dir_grid = (const float*)d_in[3];
    const float* W1 = (const float*)d_in[4];
    const float* b1 = (const float*)d_in[5];
    const float* W2 = (const float*)d_in[6];
    const float* b2 = (const float*)d_in[7];
    const float* W3 = (const float*)d_in[8];
    const float* b3 = (const float*)d_in[9];
    float* out = (float*)d_out;

    int* patP = (int*)d_ws;        // 65536 * 32 B = 2 MB
    int* patD = patP + 65536 * 8;  // 2 MB

    make_patches<<<512, 256, 0, stream>>>(pos_grid, dir_grid, patP, patD);

    const int n = in_sizes[0] / 2;   // points
    const int batches = n / 64;      // 32768 for N=2M
    const int waves = batches / NB;  // 8192
    const int blocks = waves / 4;    // 2048

    mlp_mfma_kernel<<<blocks, NTHREADS, 0, stream>>>(
        pos, dir, patP, patD, W1, b1, W2, b2, W3, b3, out);
}

// Round 9
// 155.756 us; speedup vs baseline: 1.1782x; 1.1782x over previous
//
#include <hip/hip_runtime.h>
#include <hip/hip_bf16.h>
#include <math.h>

// R9 = R8 (transpose-free 16x16x16 MFMA chain) with spill fix:
//   __launch_bounds__(256,3) -> ~170-reg cap (R8's (256,4)=128 cap spilled
//   ~110 MB/launch of scratch traffic), and a single-depth patch pipeline
//   (PB only) to halve live pipeline registers.
//   Layout identity (HW-verified in R8): 16x16x16 B-operand B[k=q*4+j][n=c]
//   == C/D layout (row=q*4+r, col=c), so layer1 D (transposed orientation)
//   feeds layer2 directly after in-register leaky+bf16 pack. No LDS transpose.
//   Patch table (R7): bilerp = 2 loads at one address, clamp folded.

#define NTHREADS 256
#define NB 4  // 64-point groups per wave

typedef __attribute__((ext_vector_type(4))) short s16x4;  // 4 bf16 = 2 VGPRs
typedef __attribute__((ext_vector_type(4))) float f32x4;
typedef __attribute__((ext_vector_type(4))) int i32x4;
typedef __attribute__((ext_vector_type(2))) int i32x2;

static __device__ __forceinline__ short f2bf(float f) {
    return __builtin_bit_cast(short, __float2bfloat16(f));  // RNE
}
static __device__ __forceinline__ int pk2(float lo, float hi) {
    unsigned short l = (unsigned short)f2bf(lo);
    unsigned short h = (unsigned short)f2bf(hi);
    return (int)(((unsigned int)h << 16) | (unsigned int)l);
}
static __device__ __forceinline__ float bflo(int u) {
    return __builtin_bit_cast(float, u << 16);
}
static __device__ __forceinline__ float bfhi(int u) {
    return __builtin_bit_cast(float, (int)(u & 0xffff0000));
}

// ---- preproc: pack 2x2 corner patches (bf16), both grids in one launch ----
// patch[id=(y0<<8)|x0]: int[8]: [0..2]=(bl<<16)|tl per ch, [3..5]=(br<<16)|tr.
__global__ __launch_bounds__(256) void make_patches(
    const float* __restrict__ gP, const float* __restrict__ gD,
    int* __restrict__ outP, int* __restrict__ outD) {
    int gid = blockIdx.x * 256 + threadIdx.x;  // 0..131071
    const float* g = (gid < 65536) ? gP : gD;
    int* po = (gid < 65536) ? outP : outD;
    int id = gid & 65535;
    int y0 = id >> 8, x0 = id & 255;
    int x1 = min(x0 + 1, 255), y1 = min(y0 + 1, 255);
    const float* tl = g + (y0 * 256 + x0) * 3;
    const float* tr = g + (y0 * 256 + x1) * 3;
    const float* bl = g + (y1 * 256 + x0) * 3;
    const float* br = g + (y1 * 256 + x1) * 3;
    i32x4 u0;
    i32x2 u1;
    u0[0] = pk2(tl[0], bl[0]);
    u0[1] = pk2(tl[1], bl[1]);
    u0[2] = pk2(tl[2], bl[2]);
    u0[3] = pk2(tr[0], br[0]);
    u1[0] = pk2(tr[1], br[1]);
    u1[1] = pk2(tr[2], br[2]);
    *(i32x4*)(po + id * 8) = u0;
    *(i32x2*)(po + id * 8 + 4) = u1;
}

static __device__ __forceinline__ void patch_issue(
    const int* __restrict__ tab, float px, float py, int* P, float& xf,
    float& yf) {
    float fx = px * 255.0f;
    float fy = py * 255.0f;
    int x0 = (int)fx;      // trunc, fx >= 0
    int y0 = (int)fy;
    xf = fx - floorf(fx);  // jnp.mod(fx,1.0), fx >= 0
    yf = fy - floorf(fy);
    int idx = (y0 << 8) | x0;
    i32x4 a = *(const i32x4*)(tab + idx * 8);
    i32x2 b = *(const i32x2*)(tab + idx * 8 + 4);
    P[0] = a[0]; P[1] = a[1]; P[2] = a[2];
    P[3] = a[3]; P[4] = b[0]; P[5] = b[1];
}

static __device__ __forceinline__ void patch_lerp(const int* P, float xf,
                                                  float yf, float* f) {
#pragma unroll
    for (int ch = 0; ch < 3; ++ch) {
        float tl = bflo(P[ch]), bl = bfhi(P[ch]);
        float tr = bflo(P[ch + 3]), br = bfhi(P[ch + 3]);
        float top = fmaf(xf, tr - tl, tl);
        float bot = fmaf(xf, br - bl, bl);
        f[ch] = fmaf(yf, bot - top, top);
    }
}

__global__ __launch_bounds__(NTHREADS, 3) void mlp_mfma_kernel(
    const float* __restrict__ pos, const float* __restrict__ dir,
    const int* __restrict__ patP, const int* __restrict__ patD,
    const float* __restrict__ W1, const float* __restrict__ b1,
    const float* __restrict__ W2, const float* __restrict__ b2,
    const float* __restrict__ W3, const float* __restrict__ b3,
    float* __restrict__ out) {
    __shared__ int lds_F[4 * 2 * 64 * 4];  // feature ping-pong, 8192 B

    const int w = threadIdx.x >> 6;
    const int lane = threadIdx.x & 63;
    const int c = lane & 15;
    const int q = lane >> 4;

    int* FB = lds_F + w * (2 * 64 * 4);

    // ---- resident weight fragments (16x16x16: A[m=lane&15][k=q*4+j]) ----
    // layer1: A[m=f][k]; k<6: W1; k==6: b1; k>=8 (q>=2): 0 -> garbage B ok.
    s16x4 A1f[4];
#pragma unroll
    for (int mt = 0; mt < 4; ++mt) {
        int f = mt * 16 + c;
        s16x4 t;
#pragma unroll
        for (int j = 0; j < 4; ++j) {
            int k = q * 4 + j;
            float v = 0.0f;
            if (k < 6) v = W1[f * 6 + k];
            else if (k == 6) v = b1[f];
            t[j] = f2bf(v);
        }
        A1f[mt] = t;
    }
    // layer2: A[m=n2][k=f]; n2 = mt*16+c, k = kt*16 + q*4 + j.
    s16x4 A2f[4][4];  // [kt][mt]
#pragma unroll
    for (int kt = 0; kt < 4; ++kt)
#pragma unroll
        for (int mt = 0; mt < 4; ++mt) {
            int n2 = mt * 16 + c;
            int k0 = kt * 16 + q * 4;
            s16x4 t;
#pragma unroll
            for (int j = 0; j < 4; ++j) t[j] = f2bf(W2[n2 * 64 + k0 + j]);
            A2f[kt][mt] = t;
        }
    // epilogue constants: n2 = mt*16 + q*4 + r (C-layout rows)
    f32x4 ci[4], w3q[4];
#pragma unroll
    for (int mt = 0; mt < 4; ++mt)
#pragma unroll
        for (int r = 0; r < 4; ++r) {
            ci[mt][r] = b2[mt * 16 + q * 4 + r];
            w3q[mt][r] = W3[mt * 16 + q * 4 + r];
        }
    const float b3s = b3[0];
    const int dbias = pk2(1.0f, 0.0f);
    const f32x4 zacc = {0.f, 0.f, 0.f, 0.f};

    const long wave_global = (long)blockIdx.x * 4 + w;
    const long base0 = wave_global * (64L * NB);
    const float2* pos2 = (const float2*)pos;
    const float2* dir2 = (const float2*)dir;

    // ---- prologue: group 0 features (serial, once), coords for group 1 ----
    float2 cp1, cd1;  // coords for group ib+1 (consumed at iter top)
    {
        float2 c0p = pos2[base0 + lane], c0d = dir2[base0 + lane];
        cp1 = pos2[base0 + 64 + lane];
        cd1 = dir2[base0 + 64 + lane];
        int P0_[12];
        float fr0[4];
        patch_issue(patP, c0p.x, c0p.y, P0_, fr0[0], fr0[1]);
        patch_issue(patD, c0d.x, c0d.y, P0_ + 6, fr0[2], fr0[3]);
        float feat[6];
        patch_lerp(P0_, fr0[0], fr0[1], feat);
        patch_lerp(P0_ + 6, fr0[2], fr0[3], feat + 3);
        i32x4 dv;
        dv[0] = pk2(feat[0], feat[1]);
        dv[1] = pk2(feat[2], feat[3]);
        dv[2] = pk2(feat[4], feat[5]);
        dv[3] = dbias;
        *(i32x4*)(FB + lane * 4) = dv;  // buf 0, row = point
    }

#pragma unroll 1
    for (int ib = 0; ib < NB; ++ib) {
        const long base = base0 + ib * 64;
        const int cur = ib & 1;

        // phase P: issue patch loads for group ib+1 (covered by phases A+B)
        int PB[12];
        float frB[4];
        patch_issue(patP, cp1.x, cp1.y, PB, frB[0], frB[1]);
        patch_issue(patD, cd1.x, cd1.y, PB + 6, frB[2], frB[3]);

        // refill coords for group ib+2 (consumed next iter top)
        {
            int mb = min(ib + 2, NB - 1);
            cp1 = pos2[base0 + mb * 64 + lane];
            cd1 = dir2[base0 + mb * 64 + lane];
        }

        // ---- 4 tiles of 16 points; fully unrolled, independent chains ----
        float s[4];
#pragma unroll
        for (int t = 0; t < 4; ++t) {
            // feature B-frag: B[k=q*4+j][n=c], point = t*16+c.
            // q=0 reads k0..3, q=1 reads k4..7; q=2,3 re-read (A is 0 there).
            i32x2 bi = *(const i32x2*)(FB + cur * 256 + (t * 16 + c) * 4 +
                                       (q & 1) * 2);
            s16x4 bfeat = __builtin_bit_cast(s16x4, bi);

            // layer 1: D1[f][p], 4 f-tiles, one K-tile
            f32x4 a1[4];
#pragma unroll
            for (int mt = 0; mt < 4; ++mt)
                a1[mt] = __builtin_amdgcn_mfma_f32_16x16x16bf16_1k(
                    A1f[mt], bfeat, zacc, 0, 0, 0);

            // leaky + pack: D1 C-layout == next B-layout (k=f), no transpose
            s16x4 bh[4];
#pragma unroll
            for (int kt = 0; kt < 4; ++kt) {
                s16x4 hv;
#pragma unroll
                for (int r = 0; r < 4; ++r) {
                    float x = a1[kt][r];
                    hv[r] = f2bf(fmaxf(x, 0.01f * x));
                }
                bh[kt] = hv;
            }

            // layer 2: D2[n2][p], C init = b2
            f32x4 a2[4];
#pragma unroll
            for (int mt = 0; mt < 4; ++mt) a2[mt] = ci[mt];
#pragma unroll
            for (int kt = 0; kt < 4; ++kt)
#pragma unroll
                for (int mt = 0; mt < 4; ++mt)
                    a2[mt] = __builtin_amdgcn_mfma_f32_16x16x16bf16_1k(
                        A2f[kt][mt], bh[kt], a2[mt], 0, 0, 0);

            // epilogue: leaky, dot W3 over this lane's 16 n2 rows, q-reduce
            float tt = 0.0f;
#pragma unroll
            for (int mt = 0; mt < 4; ++mt)
#pragma unroll
                for (int r = 0; r < 4; ++r) {
                    float x = a2[mt][r];
                    x = fmaxf(x, 0.01f * x);
                    tt = fmaf(x, w3q[mt][r], tt);
                }
            tt += __shfl_xor(tt, 16, 64);
            tt += __shfl_xor(tt, 32, 64);
            s[t] = tt;  // sum for point t*16 + c, in all quads
        }

        // lane (c,q) emits point q*16 + c with value s[q]
        float sa = (q & 1) ? s[1] : s[0];
        float sb = (q & 1) ? s[3] : s[2];
        float v = (q & 2) ? sb : sa;
        v += b3s;
        v = 1.0f / (1.0f + __expf(-v));
        out[base + q * 16 + c] = v;

        // phase F: features for group ib+1 (patch loads issued at iter top)
        {
            float feat[6];
            patch_lerp(PB, frB[0], frB[1], feat);
            patch_lerp(PB + 6, frB[2], frB[3], feat + 3);
            i32x4 dv;
            dv[0] = pk2(feat[0], feat[1]);
            dv[1] = pk2(feat[2], feat[3]);
            dv[2] = pk2(feat[4], feat[5]);
            dv[3] = dbias;
            *(i32x4*)(FB + (cur ^ 1) * 256 + lane * 4) = dv;
        }
    }
}

extern "C" void kernel_launch(void* const* d_in, const int* in_sizes, int n_in,
                              void* d_out, int out_size, void* d_ws,
                              size_t ws_size, hipStream_t stream) {
    const float* pos = (const float*)d_in[0];
    const float* dir = (const float*)d_in[1];
    const float* pos_grid = (const float*)d_in[2];
    const float* dir_grid = (const float*)d_in[3];
    const float* W1 = (const float*)d_in[4];
    const float* b1 = (const float*)d_in[5];
    const float* W2 = (const float*)d_in[6];
    const float* b2 = (const float*)d_in[7];
    const float* W3 = (const float*)d_in[8];
    const float* b3 = (const float*)d_in[9];
    float* out = (float*)d_out;

    int* patP = (int*)d_ws;        // 65536 * 32 B = 2 MB
    int* patD = patP + 65536 * 8;  // 2 MB

    make_patches<<<512, 256, 0, stream>>>(pos_grid, dir_grid, patP, patD);

    const int n = in_sizes[0] / 2;   // points
    const int batches = n / 64;      // 32768 for N=2M
    const int waves = batches / NB;  // 8192
    const int blocks = waves / 4;    // 2048

    mlp_mfma_kernel<<<blocks, NTHREADS, 0, stream>>>(
        pos, dir, patP, patD, W1, b1, W2, b2, W3, b3, out);
}